// Round 1
// baseline (21199.971 us; speedup 1.0000x reference)
//
#include <hip/hip_runtime.h>
#include <cstddef>
#include <cstdint>

#define B_    128
#define S_    52
#define D_    1024
#define H_    16
#define L_    8
#define DFF_  4096
#define DK_   64
#define T_    (B_*S_)
#define EPS_  1e-5f
#define SCALE_ 0.125f

// ---------------------------------------------------------------------------
// Embedding + BatchNorm partial stats (deterministic two-stage reduction)
// h0[b,s,:] = sep ? sep_token : action_emb[x[b,s,2]]
// part[s*B + b]       = sum over d of h0
// part[(S+s)*B + b]   = sum over d of h0^2
// mask[b*S+s]         = !pad
// ---------------------------------------------------------------------------
__global__ __launch_bounds__(256) void k_embed(const int* __restrict__ x,
    const float* __restrict__ aemb, const float* __restrict__ sept,
    float* __restrict__ h, float* __restrict__ part, int* __restrict__ mask)
{
  int row = blockIdx.x;          // b*S + s
  int b = row / S_;
  int s = row - b * S_;
  const int* xr = x + (size_t)row * 3;
  int x0 = xr[0], x1 = xr[1], x2 = xr[2];
  bool issep = (x0 == 100) && (x1 == 0) && (x2 == 2);
  bool ispad = (x0 == 100) && (x1 == 0) && (x2 == 0);
  int t = threadIdx.x;
  if (t == 0) mask[row] = ispad ? 0 : 1;
  const float* src = issep ? sept : (aemb + (size_t)x2 * D_);
  size_t base = (size_t)row * D_;
  float s1 = 0.f, s2 = 0.f;
#pragma unroll
  for (int i = 0; i < 4; ++i) {
    int d = t + i * 256;
    float v = src[d];
    h[base + d] = v;
    s1 += v;
    s2 += v * v;
  }
#pragma unroll
  for (int off = 32; off; off >>= 1) {
    s1 += __shfl_down(s1, off);
    s2 += __shfl_down(s2, off);
  }
  __shared__ float red[8];
  int lane = t & 63, wid = t >> 6;
  if (lane == 0) { red[wid] = s1; red[4 + wid] = s2; }
  __syncthreads();
  if (t == 0) {
    part[(size_t)s * B_ + b]        = red[0] + red[1] + red[2] + red[3];
    part[(size_t)(S_ + s) * B_ + b] = red[4] + red[5] + red[6] + red[7];
  }
}

__global__ __launch_bounds__(128) void k_bn_reduce(const float* __restrict__ part,
                                                   float* __restrict__ stats)
{
  int s = blockIdx.x;
  int t = threadIdx.x;          // 128 threads, one per b
  float s1 = part[(size_t)s * B_ + t];
  float s2 = part[(size_t)(S_ + s) * B_ + t];
#pragma unroll
  for (int off = 32; off; off >>= 1) {
    s1 += __shfl_down(s1, off);
    s2 += __shfl_down(s2, off);
  }
  __shared__ float red[4];
  int lane = t & 63, wid = t >> 6;
  if (lane == 0) { red[wid] = s1; red[2 + wid] = s2; }
  __syncthreads();
  if (t == 0) {
    stats[s]      = red[0] + red[1];
    stats[S_ + s] = red[2] + red[3];
  }
}

__global__ __launch_bounds__(256) void k_bn_apply(float* __restrict__ h,
    const float* __restrict__ stats, const float* __restrict__ g,
    const float* __restrict__ bb)
{
  int row = blockIdx.x;
  int s = row % S_;
  const float cnt = (float)(B_ * D_);
  float mu  = stats[s] / cnt;
  float var = stats[S_ + s] / cnt - mu * mu;
  float sc  = rsqrtf(var + EPS_) * g[s];
  float off = bb[s] - mu * sc;
  size_t base = (size_t)row * D_;
  int t = threadIdx.x;
#pragma unroll
  for (int i = 0; i < 4; ++i) {
    int d = t + i * 256;
    h[base + d] = h[base + d] * sc + off;
  }
}

// ---------------------------------------------------------------------------
// fp32 tiled GEMM:  C[M,N] = A[M,K] @ W[N,K]^T + bias[N]   (optional ReLU)
// 64x64 tile, BK=32, 256 threads, 4x4 per thread.
// ---------------------------------------------------------------------------
#define BM 64
#define BN 64
#define BK 32

__global__ __launch_bounds__(256) void k_gemm_nt(const float* __restrict__ A,
    const float* __restrict__ W, const float* __restrict__ bias,
    float* __restrict__ C, int M, int N, int K, int relu)
{
  __shared__ float As[BK][BM + 4];
  __shared__ float Ws[BK][BN + 4];
  int t  = threadIdx.x;
  int bm = blockIdx.y * BM;
  int bn = blockIdx.x * BN;
  int tx = t & 15, ty = t >> 4;
  float acc[4][4] = {{0.f}};

  int lrow = t >> 3;           // 0..31
  int lc4  = (t & 7) * 4;      // 0,4,..,28
  const float* Ap = A + (size_t)(bm + lrow) * K + lc4;
  const float* Wp = W + (size_t)(bn + lrow) * K + lc4;

  for (int kt = 0; kt < K; kt += BK) {
#pragma unroll
    for (int i = 0; i < 2; ++i) {
      int r = lrow + i * 32;
      float4 av = *reinterpret_cast<const float4*>(Ap + (size_t)i * 32 * K + kt);
      float4 wv = *reinterpret_cast<const float4*>(Wp + (size_t)i * 32 * K + kt);
      As[lc4 + 0][r] = av.x; As[lc4 + 1][r] = av.y;
      As[lc4 + 2][r] = av.z; As[lc4 + 3][r] = av.w;
      Ws[lc4 + 0][r] = wv.x; Ws[lc4 + 1][r] = wv.y;
      Ws[lc4 + 2][r] = wv.z; Ws[lc4 + 3][r] = wv.w;
    }
    __syncthreads();
#pragma unroll
    for (int kk = 0; kk < BK; ++kk) {
      float4 a = *reinterpret_cast<const float4*>(&As[kk][ty * 4]);
      float4 w = *reinterpret_cast<const float4*>(&Ws[kk][tx * 4]);
      acc[0][0] += a.x * w.x; acc[0][1] += a.x * w.y; acc[0][2] += a.x * w.z; acc[0][3] += a.x * w.w;
      acc[1][0] += a.y * w.x; acc[1][1] += a.y * w.y; acc[1][2] += a.y * w.z; acc[1][3] += a.y * w.w;
      acc[2][0] += a.z * w.x; acc[2][1] += a.z * w.y; acc[2][2] += a.z * w.z; acc[2][3] += a.z * w.w;
      acc[3][0] += a.w * w.x; acc[3][1] += a.w * w.y; acc[3][2] += a.w * w.z; acc[3][3] += a.w * w.w;
    }
    __syncthreads();
  }

  float4 bv = *reinterpret_cast<const float4*>(&bias[bn + tx * 4]);
#pragma unroll
  for (int i = 0; i < 4; ++i) {
    int m = bm + ty * 4 + i;
    float4 o;
    o.x = acc[i][0] + bv.x;
    o.y = acc[i][1] + bv.y;
    o.z = acc[i][2] + bv.z;
    o.w = acc[i][3] + bv.w;
    if (relu) {
      o.x = fmaxf(o.x, 0.f); o.y = fmaxf(o.y, 0.f);
      o.z = fmaxf(o.z, 0.f); o.w = fmaxf(o.w, 0.f);
    }
    *reinterpret_cast<float4*>(&C[(size_t)m * N + bn + tx * 4]) = o;
  }
}

// ---------------------------------------------------------------------------
// Sparse attention for one (b, head): scores -> top-5 threshold -> softmax -> PV
// ---------------------------------------------------------------------------
__global__ __launch_bounds__(256) void k_attn(const float* __restrict__ q,
    const float* __restrict__ k, const float* __restrict__ v,
    const int* __restrict__ mask, float* __restrict__ ao)
{
  __shared__ float qs[S_][DK_];
  __shared__ float ks[S_][DK_ + 1];
  __shared__ float vs[S_][DK_];
  __shared__ float sc[S_][S_ + 1];
  __shared__ int vm[S_];
  int blk = blockIdx.x;
  int b  = blk >> 4;       // / H_
  int hh = blk & 15;       // % H_
  int t = threadIdx.x;
  const float* qp = q + (size_t)b * S_ * D_ + hh * DK_;
  const float* kp = k + (size_t)b * S_ * D_ + hh * DK_;
  const float* vp = v + (size_t)b * S_ * D_ + hh * DK_;
  for (int e = t; e < S_ * DK_; e += 256) {
    int r = e >> 6, c = e & 63;
    qs[r][c] = qp[(size_t)r * D_ + c];
    ks[r][c] = kp[(size_t)r * D_ + c];
    vs[r][c] = vp[(size_t)r * D_ + c];
  }
  if (t < S_) vm[t] = mask[b * S_ + t];
  __syncthreads();

  for (int e = t; e < S_ * S_; e += 256) {
    int r = e / S_, c = e - r * S_;
    float acc = 0.f;
#pragma unroll
    for (int d = 0; d < DK_; ++d) acc += qs[r][d] * ks[c][d];
    sc[r][c] = vm[c] ? acc * SCALE_ : -1e9f;
  }
  __syncthreads();

  if (t < S_) {
    // top-5 values (insertion), thr = 5th largest (jax.lax.top_k semantics)
    float v0 = -3e38f, v1 = -3e38f, v2 = -3e38f, v3 = -3e38f, v4 = -3e38f;
    for (int c = 0; c < S_; ++c) {
      float xv = sc[t][c];
      if      (xv > v0) { v4 = v3; v3 = v2; v2 = v1; v1 = v0; v0 = xv; }
      else if (xv > v1) { v4 = v3; v3 = v2; v2 = v1; v1 = xv; }
      else if (xv > v2) { v4 = v3; v3 = v2; v2 = xv; }
      else if (xv > v3) { v4 = v3; v3 = xv; }
      else if (xv > v4) { v4 = xv; }
    }
    float thr = v4;
    // sparse = scores * (scores >= thr); dropped entries become exact 0.0
    // softmax row max = max(best_kept, 0) since zeros always exist
    float m = fmaxf(v0, 0.f);
    float denom = 0.f;
    for (int c = 0; c < S_; ++c) {
      float xv = sc[t][c];
      float sp = (xv >= thr) ? xv : 0.f;
      float e = __expf(sp - m);
      denom += e;
      sc[t][c] = e;
    }
    float inv = 1.f / denom;
    for (int c = 0; c < S_; ++c) sc[t][c] *= inv;
  }
  __syncthreads();

  float* aop = ao + (size_t)b * S_ * D_ + hh * DK_;
  for (int e = t; e < S_ * DK_; e += 256) {
    int r = e >> 6, c = e & 63;
    float acc = 0.f;
#pragma unroll 4
    for (int j = 0; j < S_; ++j) acc += sc[r][j] * vs[j][c];
    aop[(size_t)r * D_ + c] = acc;
  }
}

// ---------------------------------------------------------------------------
// h = LayerNorm(h + r) * g + b   (row-wise over D)
// ---------------------------------------------------------------------------
__global__ __launch_bounds__(256) void k_add_ln(float* __restrict__ h,
    const float* __restrict__ r, const float* __restrict__ g,
    const float* __restrict__ bb)
{
  int row = blockIdx.x;
  size_t base = (size_t)row * D_;
  int t = threadIdx.x;
  float xs[4];
  float s1 = 0.f, s2 = 0.f;
#pragma unroll
  for (int i = 0; i < 4; ++i) {
    int d = t + i * 256;
    float xv = h[base + d] + r[base + d];
    xs[i] = xv;
    s1 += xv;
    s2 += xv * xv;
  }
#pragma unroll
  for (int off = 32; off; off >>= 1) {
    s1 += __shfl_down(s1, off);
    s2 += __shfl_down(s2, off);
  }
  __shared__ float red[8];
  int lane = t & 63, wid = t >> 6;
  if (lane == 0) { red[wid] = s1; red[4 + wid] = s2; }
  __syncthreads();
  if (t == 0) {
    red[0] = red[0] + red[1] + red[2] + red[3];
    red[4] = red[4] + red[5] + red[6] + red[7];
  }
  __syncthreads();
  float mean = red[0] / (float)D_;
  float var  = red[4] / (float)D_ - mean * mean;
  float inv  = rsqrtf(var + EPS_);
#pragma unroll
  for (int i = 0; i < 4; ++i) {
    int d = t + i * 256;
    h[base + d] = (xs[i] - mean) * inv * g[d] + bb[d];
  }
}

// ---------------------------------------------------------------------------
// y[b,:] = h[b, S-1, :] @ Wout^T + bout     (3 outputs per b)
// ---------------------------------------------------------------------------
__global__ __launch_bounds__(256) void k_final(const float* __restrict__ h,
    const float* __restrict__ Wout, const float* __restrict__ bout,
    float* __restrict__ y)
{
  int b = blockIdx.x;
  const float* hr = h + (size_t)(b * S_ + (S_ - 1)) * D_;
  int t = threadIdx.x;
  float p0 = 0.f, p1 = 0.f, p2 = 0.f;
  for (int d = t; d < D_; d += 256) {
    float xv = hr[d];
    p0 += xv * Wout[d];
    p1 += xv * Wout[D_ + d];
    p2 += xv * Wout[2 * D_ + d];
  }
#pragma unroll
  for (int off = 32; off; off >>= 1) {
    p0 += __shfl_down(p0, off);
    p1 += __shfl_down(p1, off);
    p2 += __shfl_down(p2, off);
  }
  __shared__ float red[12];
  int lane = t & 63, wid = t >> 6;
  if (lane == 0) { red[wid] = p0; red[4 + wid] = p1; red[8 + wid] = p2; }
  __syncthreads();
  if (t == 0) {
    y[b * 3 + 0] = red[0] + red[1] + red[2]  + red[3]  + bout[0];
    y[b * 3 + 1] = red[4] + red[5] + red[6]  + red[7]  + bout[1];
    y[b * 3 + 2] = red[8] + red[9] + red[10] + red[11] + bout[2];
  }
}

// ---------------------------------------------------------------------------
extern "C" void kernel_launch(void* const* d_in, const int* in_sizes, int n_in,
                              void* d_out, int out_size, void* d_ws, size_t ws_size,
                              hipStream_t stream)
{
  const int*   x    = (const int*)d_in[0];
  const float* aemb = (const float*)d_in[1];
  const float* sept = (const float*)d_in[2];
  const float* bng  = (const float*)d_in[3];
  const float* bnb  = (const float*)d_in[4];
  const float* Wq = (const float*)d_in[5];  const float* bq = (const float*)d_in[6];
  const float* Wk = (const float*)d_in[7];  const float* bk = (const float*)d_in[8];
  const float* Wv = (const float*)d_in[9];  const float* bv = (const float*)d_in[10];
  const float* Wo = (const float*)d_in[11]; const float* bo = (const float*)d_in[12];
  const float* W1 = (const float*)d_in[13]; const float* b1 = (const float*)d_in[14];
  const float* W2 = (const float*)d_in[15]; const float* b2 = (const float*)d_in[16];
  const float* ln1g = (const float*)d_in[17]; const float* ln1b = (const float*)d_in[18];
  const float* ln2g = (const float*)d_in[19]; const float* ln2b = (const float*)d_in[20];
  const float* Wout = (const float*)d_in[21]; const float* bout = (const float*)d_in[22];
  float* out = (float*)d_out;

  float* ws = (float*)d_ws;
  const size_t TD = (size_t)T_ * D_;
  float* h    = ws;
  float* qb   = ws + TD;
  float* kb   = ws + 2 * TD;
  float* vb   = ws + 3 * TD;
  float* ao   = ws + 4 * TD;
  float* tmp  = ws + 5 * TD;
  float* ff   = ws + TD;                 // aliases q/k/v/ao (dead when ff is live)
  float* stats = ws + 6 * TD;            // 2*S
  float* part  = ws + 6 * TD + 128;      // 2*S*B
  int*   mask  = (int*)(ws + 6 * TD + 128 + 2 * S_ * B_);

  k_embed<<<T_, 256, 0, stream>>>(x, aemb, sept, h, part, mask);
  k_bn_reduce<<<S_, 128, 0, stream>>>(part, stats);
  k_bn_apply<<<T_, 256, 0, stream>>>(h, stats, bng, bnb);

  const size_t DD = (size_t)D_ * D_;
  const size_t DF = (size_t)DFF_ * D_;
  for (int l = 0; l < L_; ++l) {
    k_gemm_nt<<<dim3(D_ / BN, T_ / BM), 256, 0, stream>>>(h, Wq + l * DD, bq + l * D_, qb, T_, D_, D_, 0);
    k_gemm_nt<<<dim3(D_ / BN, T_ / BM), 256, 0, stream>>>(h, Wk + l * DD, bk + l * D_, kb, T_, D_, D_, 0);
    k_gemm_nt<<<dim3(D_ / BN, T_ / BM), 256, 0, stream>>>(h, Wv + l * DD, bv + l * D_, vb, T_, D_, D_, 0);
    k_attn<<<B_ * H_, 256, 0, stream>>>(qb, kb, vb, mask, ao);
    k_gemm_nt<<<dim3(D_ / BN, T_ / BM), 256, 0, stream>>>(ao, Wo + l * DD, bo + l * D_, tmp, T_, D_, D_, 0);
    k_add_ln<<<T_, 256, 0, stream>>>(h, tmp, ln1g + l * D_, ln1b + l * D_);
    k_gemm_nt<<<dim3(DFF_ / BN, T_ / BM), 256, 0, stream>>>(h, W1 + l * DF, b1 + l * DFF_, ff, T_, DFF_, D_, 1);
    k_gemm_nt<<<dim3(D_ / BN, T_ / BM), 256, 0, stream>>>(ff, W2 + l * DF, b2 + l * D_, tmp, T_, D_, DFF_, 0);
    k_add_ln<<<T_, 256, 0, stream>>>(h, tmp, ln2g + l * D_, ln2b + l * D_);
  }
  k_final<<<B_, 256, 0, stream>>>(h, Wout, bout, out);
}

// Round 2
// 3513.361 us; speedup vs baseline: 6.0341x; 6.0341x over previous
//
#include <hip/hip_runtime.h>
#include <cstddef>
#include <cstdint>

#define B_    128
#define S_    52
#define D_    1024
#define H_    16
#define L_    8
#define DFF_  4096
#define DK_   64
#define T_    (B_*S_)
#define EPS_  1e-5f
#define SCALE_ 0.125f

typedef unsigned short ushortx4 __attribute__((ext_vector_type(4)));
typedef short  bf16x8 __attribute__((ext_vector_type(8)));
typedef float  f32x4  __attribute__((ext_vector_type(4)));

__device__ __forceinline__ unsigned short f2b(float f) {
  unsigned int u = __builtin_bit_cast(unsigned int, f);
  u = u + 0x7fffu + ((u >> 16) & 1u);
  return (unsigned short)(u >> 16);
}
__device__ __forceinline__ float b2f(unsigned short b) {
  unsigned int u = ((unsigned int)b) << 16;
  return __builtin_bit_cast(float, u);
}
__device__ __forceinline__ void gload16(const void* g, void* l) {
  __builtin_amdgcn_global_load_lds((const __attribute__((address_space(1))) unsigned int*)g,
      (__attribute__((address_space(3))) unsigned int*)l, 16, 0, 0);
}

// ---------------------------------------------------------------------------
// Embedding + BN partial stats
// ---------------------------------------------------------------------------
__global__ __launch_bounds__(256) void k_embed(const int* __restrict__ x,
    const float* __restrict__ aemb, const float* __restrict__ sept,
    float* __restrict__ h, float* __restrict__ part, int* __restrict__ mask)
{
  int row = blockIdx.x;
  int b = row / S_;
  int s = row - b * S_;
  const int* xr = x + (size_t)row * 3;
  int x0 = xr[0], x1 = xr[1], x2 = xr[2];
  bool issep = (x0 == 100) && (x1 == 0) && (x2 == 2);
  bool ispad = (x0 == 100) && (x1 == 0) && (x2 == 0);
  int t = threadIdx.x;
  if (t == 0) mask[row] = ispad ? 0 : 1;
  const float* src = issep ? sept : (aemb + (size_t)x2 * D_);
  size_t base = (size_t)row * D_;
  float s1 = 0.f, s2 = 0.f;
#pragma unroll
  for (int i = 0; i < 4; ++i) {
    int d = t + i * 256;
    float v = src[d];
    h[base + d] = v;
    s1 += v;
    s2 += v * v;
  }
#pragma unroll
  for (int off = 32; off; off >>= 1) {
    s1 += __shfl_down(s1, off);
    s2 += __shfl_down(s2, off);
  }
  __shared__ float red[8];
  int lane = t & 63, wid = t >> 6;
  if (lane == 0) { red[wid] = s1; red[4 + wid] = s2; }
  __syncthreads();
  if (t == 0) {
    part[(size_t)s * B_ + b]        = red[0] + red[1] + red[2] + red[3];
    part[(size_t)(S_ + s) * B_ + b] = red[4] + red[5] + red[6] + red[7];
  }
}

__global__ __launch_bounds__(128) void k_bn_reduce(const float* __restrict__ part,
                                                   float* __restrict__ stats)
{
  int s = blockIdx.x;
  int t = threadIdx.x;
  float s1 = part[(size_t)s * B_ + t];
  float s2 = part[(size_t)(S_ + s) * B_ + t];
#pragma unroll
  for (int off = 32; off; off >>= 1) {
    s1 += __shfl_down(s1, off);
    s2 += __shfl_down(s2, off);
  }
  __shared__ float red[4];
  int lane = t & 63, wid = t >> 6;
  if (lane == 0) { red[wid] = s1; red[2 + wid] = s2; }
  __syncthreads();
  if (t == 0) {
    stats[s]      = red[0] + red[1];
    stats[S_ + s] = red[2] + red[3];
  }
}

__global__ __launch_bounds__(256) void k_bn_apply(float* __restrict__ h,
    const float* __restrict__ stats, const float* __restrict__ g,
    const float* __restrict__ bb)
{
  int row = blockIdx.x;
  int s = row % S_;
  const float cnt = (float)(B_ * D_);
  float mu  = stats[s] / cnt;
  float var = stats[S_ + s] / cnt - mu * mu;
  float sc  = rsqrtf(var + EPS_) * g[s];
  float off = bb[s] - mu * sc;
  size_t base = (size_t)row * D_;
  int t = threadIdx.x;
#pragma unroll
  for (int i = 0; i < 4; ++i) {
    int d = t + i * 256;
    h[base + d] = h[base + d] * sc + off;
  }
}

// ---------------------------------------------------------------------------
// fp32 -> bf16 converters
// ---------------------------------------------------------------------------
__global__ __launch_bounds__(256) void k_f2b(const float* __restrict__ src,
    unsigned short* __restrict__ dst, int n4)
{
  int i = blockIdx.x * 256 + threadIdx.x;
  if (i >= n4) return;
  float4 v = *reinterpret_cast<const float4*>(src + (size_t)i * 4);
  ushortx4 o = { f2b(v.x), f2b(v.y), f2b(v.z), f2b(v.w) };
  *reinterpret_cast<ushortx4*>(dst + (size_t)i * 4) = o;
}

// per-layer fused weight conversion: [q|k|v|o|w1|w2] -> wbuf
__global__ __launch_bounds__(256) void k_wconv(
    const float* __restrict__ wq, const float* __restrict__ wk,
    const float* __restrict__ wv, const float* __restrict__ wo,
    const float* __restrict__ w1, const float* __restrict__ w2,
    unsigned short* __restrict__ out)
{
  const size_t DD = (size_t)D_ * D_;
  const size_t DF = (size_t)DFF_ * D_;
  const size_t total = 4 * DD + 2 * DF;
  size_t stride = (size_t)gridDim.x * 256 * 4;
  for (size_t i = ((size_t)blockIdx.x * 256 + threadIdx.x) * 4; i < total; i += stride) {
    const float* src; size_t off;
    if      (i < DD)          { src = wq; off = i; }
    else if (i < 2 * DD)      { src = wk; off = i - DD; }
    else if (i < 3 * DD)      { src = wv; off = i - 2 * DD; }
    else if (i < 4 * DD)      { src = wo; off = i - 3 * DD; }
    else if (i < 4 * DD + DF) { src = w1; off = i - 4 * DD; }
    else                      { src = w2; off = i - 4 * DD - DF; }
    float4 v = *reinterpret_cast<const float4*>(src + off);
    ushortx4 o = { f2b(v.x), f2b(v.y), f2b(v.z), f2b(v.w) };
    *reinterpret_cast<ushortx4*>(out + i) = o;
  }
}

// concat per-layer qkv biases -> bqkv_all[L][3072]
__global__ __launch_bounds__(256) void k_bcat(const float* __restrict__ bq,
    const float* __restrict__ bk, const float* __restrict__ bv,
    float* __restrict__ out)
{
  int i = blockIdx.x * 256 + threadIdx.x;    // < L*3072
  int l = i / 3072, j = i - l * 3072;
  float v = (j < D_) ? bq[l * D_ + j] : (j < 2 * D_) ? bk[l * D_ + j - D_]
                                                     : bv[l * D_ + j - 2 * D_];
  out[i] = v;
}

// ---------------------------------------------------------------------------
// bf16 MFMA GEMM: C[M,N] = A[M,K] @ Wt[N,K]^T + bias
// 128x128 tile, BK=32, 4 waves, 4x4 16x16x32 frags per wave, global_load_lds.
// ---------------------------------------------------------------------------
template<int RELU, int OUTBF16>
__global__ __launch_bounds__(256) void k_gemm_bf16(
    const unsigned short* __restrict__ A, const unsigned short* __restrict__ Wt,
    const float* __restrict__ bias, void* __restrict__ C,
    int M, int N, int K, int ldc)
{
  __shared__ unsigned short As[128][32];
  __shared__ unsigned short Bs[128][32];
  int t = threadIdx.x;
  int lane = t & 63;
  int wid = t >> 6;
  int bm = blockIdx.y * 128;
  int bn = blockIdx.x * 128;
  int wr = wid >> 1, wc = wid & 1;

  const unsigned short* Ag = A + (size_t)(bm + wid * 32 + (lane >> 2)) * K + (lane & 3) * 8;
  const unsigned short* Bg = Wt + (size_t)(bn + wid * 32 + (lane >> 2)) * K + (lane & 3) * 8;

  f32x4 acc[4][4] = {};
  int fr = lane & 15;
  int kc = lane >> 4;

  for (int kt = 0; kt < K; kt += 32) {
#pragma unroll
    for (int j = 0; j < 2; ++j) {
      gload16(Ag + (size_t)j * 16 * K + kt, &As[wid * 32 + j * 16][0]);
      gload16(Bg + (size_t)j * 16 * K + kt, &Bs[wid * 32 + j * 16][0]);
    }
    __syncthreads();
    bf16x8 af[4], bfv[4];
#pragma unroll
    for (int m = 0; m < 4; ++m)
      af[m] = *reinterpret_cast<const bf16x8*>(&As[wr * 64 + m * 16 + fr][kc * 8]);
#pragma unroll
    for (int n = 0; n < 4; ++n)
      bfv[n] = *reinterpret_cast<const bf16x8*>(&Bs[wc * 64 + n * 16 + fr][kc * 8]);
#pragma unroll
    for (int m = 0; m < 4; ++m)
#pragma unroll
      for (int n = 0; n < 4; ++n)
        acc[m][n] = __builtin_amdgcn_mfma_f32_16x16x32_bf16(af[m], bfv[n], acc[m][n], 0, 0, 0);
    __syncthreads();
  }

  int fq = lane >> 4;
#pragma unroll
  for (int n = 0; n < 4; ++n) {
    int col = bn + wc * 64 + n * 16 + fr;
    float bv = bias[col];
#pragma unroll
    for (int m = 0; m < 4; ++m) {
      int row = bm + wr * 64 + m * 16 + fq * 4;
#pragma unroll
      for (int j = 0; j < 4; ++j) {
        float v = acc[m][n][j] + bv;
        if (RELU) v = fmaxf(v, 0.f);
        if (OUTBF16)
          ((unsigned short*)C)[(size_t)(row + j) * ldc + col] = f2b(v);
        else
          ((float*)C)[(size_t)(row + j) * ldc + col] = v;
      }
    }
  }
}

// ---------------------------------------------------------------------------
// Sparse attention: bf16 q,k,v (fused [T][3072] layout) -> bf16 ao
// ---------------------------------------------------------------------------
__global__ __launch_bounds__(256) void k_attn(const unsigned short* __restrict__ qkv,
    const int* __restrict__ mask, unsigned short* __restrict__ ao)
{
  __shared__ float qs[S_][DK_];
  __shared__ float ks[S_][DK_ + 1];
  __shared__ float vs[S_][DK_];
  __shared__ float sc[S_][S_ + 1];
  __shared__ int vm[S_];
  int blk = blockIdx.x;
  int b  = blk >> 4;
  int hh = blk & 15;
  int t = threadIdx.x;
  const unsigned short* base = qkv + (size_t)b * S_ * 3072 + hh * DK_;
  for (int e = t; e < S_ * DK_; e += 256) {
    int r = e >> 6, c = e & 63;
    size_t ro = (size_t)r * 3072;
    qs[r][c] = b2f(base[ro + c]);
    ks[r][c] = b2f(base[ro + 1024 + c]);
    vs[r][c] = b2f(base[ro + 2048 + c]);
  }
  if (t < S_) vm[t] = mask[b * S_ + t];
  __syncthreads();

  for (int e = t; e < S_ * S_; e += 256) {
    int r = e / S_, c = e - r * S_;
    float acc = 0.f;
#pragma unroll
    for (int d = 0; d < DK_; ++d) acc += qs[r][d] * ks[c][d];
    sc[r][c] = vm[c] ? acc * SCALE_ : -1e9f;
  }
  __syncthreads();

  if (t < S_) {
    float v0 = -3e38f, v1 = -3e38f, v2 = -3e38f, v3 = -3e38f, v4 = -3e38f;
    for (int c = 0; c < S_; ++c) {
      float xv = sc[t][c];
      if      (xv > v0) { v4 = v3; v3 = v2; v2 = v1; v1 = v0; v0 = xv; }
      else if (xv > v1) { v4 = v3; v3 = v2; v2 = v1; v1 = xv; }
      else if (xv > v2) { v4 = v3; v3 = v2; v2 = xv; }
      else if (xv > v3) { v4 = v3; v3 = xv; }
      else if (xv > v4) { v4 = xv; }
    }
    float thr = v4;
    float m = fmaxf(v0, 0.f);
    float denom = 0.f;
    for (int c = 0; c < S_; ++c) {
      float xv = sc[t][c];
      float sp = (xv >= thr) ? xv : 0.f;
      float e = __expf(sp - m);
      denom += e;
      sc[t][c] = e;
    }
    float inv = 1.f / denom;
    for (int c = 0; c < S_; ++c) sc[t][c] *= inv;
  }
  __syncthreads();

  unsigned short* aop = ao + (size_t)b * S_ * D_ + hh * DK_;
  for (int e = t; e < S_ * DK_; e += 256) {
    int r = e >> 6, c = e & 63;
    float acc = 0.f;
#pragma unroll 4
    for (int j = 0; j < S_; ++j) acc += sc[r][j] * vs[j][c];
    aop[(size_t)r * D_ + c] = f2b(acc);
  }
}

// ---------------------------------------------------------------------------
// h = LayerNorm(h + r) * g + b
// ---------------------------------------------------------------------------
__global__ __launch_bounds__(256) void k_add_ln(float* __restrict__ h,
    const float* __restrict__ r, const float* __restrict__ g,
    const float* __restrict__ bb)
{
  int row = blockIdx.x;
  size_t base = (size_t)row * D_;
  int t = threadIdx.x;
  float xs[4];
  float s1 = 0.f, s2 = 0.f;
#pragma unroll
  for (int i = 0; i < 4; ++i) {
    int d = t + i * 256;
    float xv = h[base + d] + r[base + d];
    xs[i] = xv;
    s1 += xv;
    s2 += xv * xv;
  }
#pragma unroll
  for (int off = 32; off; off >>= 1) {
    s1 += __shfl_down(s1, off);
    s2 += __shfl_down(s2, off);
  }
  __shared__ float red[8];
  int lane = t & 63, wid = t >> 6;
  if (lane == 0) { red[wid] = s1; red[4 + wid] = s2; }
  __syncthreads();
  if (t == 0) {
    red[0] = red[0] + red[1] + red[2] + red[3];
    red[4] = red[4] + red[5] + red[6] + red[7];
  }
  __syncthreads();
  float mean = red[0] / (float)D_;
  float var  = red[4] / (float)D_ - mean * mean;
  float inv  = rsqrtf(var + EPS_);
#pragma unroll
  for (int i = 0; i < 4; ++i) {
    int d = t + i * 256;
    h[base + d] = (xs[i] - mean) * inv * g[d] + bb[d];
  }
}

// ---------------------------------------------------------------------------
__global__ __launch_bounds__(256) void k_final(const float* __restrict__ h,
    const float* __restrict__ Wout, const float* __restrict__ bout,
    float* __restrict__ y)
{
  int b = blockIdx.x;
  const float* hr = h + (size_t)(b * S_ + (S_ - 1)) * D_;
  int t = threadIdx.x;
  float p0 = 0.f, p1 = 0.f, p2 = 0.f;
  for (int d = t; d < D_; d += 256) {
    float xv = hr[d];
    p0 += xv * Wout[d];
    p1 += xv * Wout[D_ + d];
    p2 += xv * Wout[2 * D_ + d];
  }
#pragma unroll
  for (int off = 32; off; off >>= 1) {
    p0 += __shfl_down(p0, off);
    p1 += __shfl_down(p1, off);
    p2 += __shfl_down(p2, off);
  }
  __shared__ float red[12];
  int lane = t & 63, wid = t >> 6;
  if (lane == 0) { red[wid] = p0; red[4 + wid] = p1; red[8 + wid] = p2; }
  __syncthreads();
  if (t == 0) {
    y[b * 3 + 0] = red[0] + red[1] + red[2]  + red[3]  + bout[0];
    y[b * 3 + 1] = red[4] + red[5] + red[6]  + red[7]  + bout[1];
    y[b * 3 + 2] = red[8] + red[9] + red[10] + red[11] + bout[2];
  }
}

// ---------------------------------------------------------------------------
extern "C" void kernel_launch(void* const* d_in, const int* in_sizes, int n_in,
                              void* d_out, int out_size, void* d_ws, size_t ws_size,
                              hipStream_t stream)
{
  const int*   x    = (const int*)d_in[0];
  const float* aemb = (const float*)d_in[1];
  const float* sept = (const float*)d_in[2];
  const float* bng  = (const float*)d_in[3];
  const float* bnb  = (const float*)d_in[4];
  const float* Wq = (const float*)d_in[5];  const float* bq = (const float*)d_in[6];
  const float* Wk = (const float*)d_in[7];  const float* bk = (const float*)d_in[8];
  const float* Wv = (const float*)d_in[9];  const float* bv = (const float*)d_in[10];
  const float* Wo = (const float*)d_in[11]; const float* bo = (const float*)d_in[12];
  const float* W1 = (const float*)d_in[13]; const float* b1 = (const float*)d_in[14];
  const float* W2 = (const float*)d_in[15]; const float* b2 = (const float*)d_in[16];
  const float* ln1g = (const float*)d_in[17]; const float* ln1b = (const float*)d_in[18];
  const float* ln2g = (const float*)d_in[19]; const float* ln2b = (const float*)d_in[20];
  const float* Wout = (const float*)d_in[21]; const float* bout = (const float*)d_in[22];
  float* out = (float*)d_out;

  float* ws = (float*)d_ws;
  const size_t TD = (size_t)T_ * D_;              // 6,815,744
  const size_t DD = (size_t)D_ * D_;
  const size_t DF = (size_t)DFF_ * D_;
  float* h   = ws;                                // TD f32
  float* tmp = ws + TD;                           // TD f32
  unsigned short* hb   = (unsigned short*)(ws + 2 * TD);            // TD bf16
  unsigned short* qkvb = (unsigned short*)(ws + 2 * TD + TD / 2);   // 3TD bf16
  unsigned short* aob  = (unsigned short*)(ws + 4 * TD);            // TD bf16
  unsigned short* ffb  = (unsigned short*)(ws + 4 * TD + TD / 2);   // 4TD bf16
  unsigned short* wbuf = (unsigned short*)(ws + 6 * TD + TD / 2);   // 12.58M bf16
  float* bqkv = ws + 6 * TD + TD / 2 + (4 * DD + 2 * DF) / 2;       // L*3072 f32
  float* stats = bqkv + L_ * 3072;                // 2*S
  float* part  = stats + 2 * S_;                  // 2*S*B
  int*   mask  = (int*)(part + 2 * S_ * B_);      // T ints

  k_embed<<<T_, 256, 0, stream>>>(x, aemb, sept, h, part, mask);
  k_bn_reduce<<<S_, 128, 0, stream>>>(part, stats);
  k_bn_apply<<<T_, 256, 0, stream>>>(h, stats, bng, bnb);
  k_bcat<<<(L_ * 3072) / 256, 256, 0, stream>>>(bq, bk, bv, bqkv);

  for (int l = 0; l < L_; ++l) {
    k_wconv<<<3072, 256, 0, stream>>>(Wq + l * DD, Wk + l * DD, Wv + l * DD,
                                      Wo + l * DD, W1 + l * DF, W2 + l * DF, wbuf);
    k_f2b<<<(int)(TD / 4 / 256), 256, 0, stream>>>(h, hb, (int)(TD / 4));
    k_gemm_bf16<0, 1><<<dim3(24, 52), 256, 0, stream>>>(hb, wbuf, bqkv + l * 3072,
        qkvb, T_, 3072, D_, 3072);
    k_attn<<<B_ * H_, 256, 0, stream>>>(qkvb, mask, aob);
    k_gemm_bf16<0, 0><<<dim3(8, 52), 256, 0, stream>>>(aob, wbuf + 3 * DD, bo + l * D_,
        tmp, T_, D_, D_, D_);
    k_add_ln<<<T_, 256, 0, stream>>>(h, tmp, ln1g + l * D_, ln1b + l * D_);
    k_f2b<<<(int)(TD / 4 / 256), 256, 0, stream>>>(h, hb, (int)(TD / 4));
    k_gemm_bf16<1, 1><<<dim3(32, 52), 256, 0, stream>>>(hb, wbuf + 4 * DD, b1 + l * DFF_,
        ffb, T_, DFF_, D_, DFF_);
    k_gemm_bf16<0, 0><<<dim3(8, 52), 256, 0, stream>>>(ffb, wbuf + 4 * DD + DF, b2 + l * D_,
        tmp, T_, D_, DFF_, D_);
    k_add_ln<<<T_, 256, 0, stream>>>(h, tmp, ln2g + l * D_, ln2b + l * D_);
  }
  k_final<<<B_, 256, 0, stream>>>(h, Wout, bout, out);
}

// Round 3
// 2942.561 us; speedup vs baseline: 7.2046x; 1.1940x over previous
//
#include <hip/hip_runtime.h>
#include <cstddef>
#include <cstdint>

#define B_    128
#define S_    52
#define D_    1024
#define H_    16
#define L_    8
#define DFF_  4096
#define DK_   64
#define T_    (B_*S_)
#define EPS_  1e-5f
#define SCALE_ 0.125f

typedef unsigned short ushortx4 __attribute__((ext_vector_type(4)));
typedef short  bf16x8 __attribute__((ext_vector_type(8)));
typedef float  f32x4  __attribute__((ext_vector_type(4)));

__device__ __forceinline__ unsigned short f2b(float f) {
  unsigned int u = __builtin_bit_cast(unsigned int, f);
  u = u + 0x7fffu + ((u >> 16) & 1u);
  return (unsigned short)(u >> 16);
}
__device__ __forceinline__ float b2f(unsigned short b) {
  unsigned int u = ((unsigned int)b) << 16;
  return __builtin_bit_cast(float, u);
}
__device__ __forceinline__ void gload16(const void* g, void* l) {
  __builtin_amdgcn_global_load_lds((const __attribute__((address_space(1))) unsigned int*)g,
      (__attribute__((address_space(3))) unsigned int*)l, 16, 0, 0);
}

// ---------------------------------------------------------------------------
// Embedding + BN partial stats
// ---------------------------------------------------------------------------
__global__ __launch_bounds__(256) void k_embed(const int* __restrict__ x,
    const float* __restrict__ aemb, const float* __restrict__ sept,
    float* __restrict__ h, float* __restrict__ part, int* __restrict__ mask)
{
  int row = blockIdx.x;
  int b = row / S_;
  int s = row - b * S_;
  const int* xr = x + (size_t)row * 3;
  int x0 = xr[0], x1 = xr[1], x2 = xr[2];
  bool issep = (x0 == 100) && (x1 == 0) && (x2 == 2);
  bool ispad = (x0 == 100) && (x1 == 0) && (x2 == 0);
  int t = threadIdx.x;
  if (t == 0) mask[row] = ispad ? 0 : 1;
  const float* src = issep ? sept : (aemb + (size_t)x2 * D_);
  size_t base = (size_t)row * D_;
  float s1 = 0.f, s2 = 0.f;
#pragma unroll
  for (int i = 0; i < 4; ++i) {
    int d = t + i * 256;
    float v = src[d];
    h[base + d] = v;
    s1 += v;
    s2 += v * v;
  }
#pragma unroll
  for (int off = 32; off; off >>= 1) {
    s1 += __shfl_down(s1, off);
    s2 += __shfl_down(s2, off);
  }
  __shared__ float red[8];
  int lane = t & 63, wid = t >> 6;
  if (lane == 0) { red[wid] = s1; red[4 + wid] = s2; }
  __syncthreads();
  if (t == 0) {
    part[(size_t)s * B_ + b]        = red[0] + red[1] + red[2] + red[3];
    part[(size_t)(S_ + s) * B_ + b] = red[4] + red[5] + red[6] + red[7];
  }
}

__global__ __launch_bounds__(128) void k_bn_reduce(const float* __restrict__ part,
                                                   float* __restrict__ stats)
{
  int s = blockIdx.x;
  int t = threadIdx.x;
  float s1 = part[(size_t)s * B_ + t];
  float s2 = part[(size_t)(S_ + s) * B_ + t];
#pragma unroll
  for (int off = 32; off; off >>= 1) {
    s1 += __shfl_down(s1, off);
    s2 += __shfl_down(s2, off);
  }
  __shared__ float red[4];
  int lane = t & 63, wid = t >> 6;
  if (lane == 0) { red[wid] = s1; red[2 + wid] = s2; }
  __syncthreads();
  if (t == 0) {
    stats[s]      = red[0] + red[1];
    stats[S_ + s] = red[2] + red[3];
  }
}

// BN apply, writes fp32 h and bf16 hb
__global__ __launch_bounds__(256) void k_bn_apply(float* __restrict__ h,
    const float* __restrict__ stats, const float* __restrict__ g,
    const float* __restrict__ bb, unsigned short* __restrict__ hb)
{
  int row = blockIdx.x;
  int s = row % S_;
  const float cnt = (float)(B_ * D_);
  float mu  = stats[s] / cnt;
  float var = stats[S_ + s] / cnt - mu * mu;
  float sc  = rsqrtf(var + EPS_) * g[s];
  float off = bb[s] - mu * sc;
  size_t base = (size_t)row * D_;
  int t = threadIdx.x;
#pragma unroll
  for (int i = 0; i < 4; ++i) {
    int d = t + i * 256;
    float v = h[base + d] * sc + off;
    h[base + d] = v;
    hb[base + d] = f2b(v);
  }
}

// per-layer fused weight conversion: [q|k|v|o|w1|w2] -> wbuf
__global__ __launch_bounds__(256) void k_wconv(
    const float* __restrict__ wq, const float* __restrict__ wk,
    const float* __restrict__ wv, const float* __restrict__ wo,
    const float* __restrict__ w1, const float* __restrict__ w2,
    unsigned short* __restrict__ out)
{
  const size_t DD = (size_t)D_ * D_;
  const size_t DF = (size_t)DFF_ * D_;
  const size_t total = 4 * DD + 2 * DF;
  size_t stride = (size_t)gridDim.x * 256 * 4;
  for (size_t i = ((size_t)blockIdx.x * 256 + threadIdx.x) * 4; i < total; i += stride) {
    const float* src; size_t off;
    if      (i < DD)          { src = wq; off = i; }
    else if (i < 2 * DD)      { src = wk; off = i - DD; }
    else if (i < 3 * DD)      { src = wv; off = i - 2 * DD; }
    else if (i < 4 * DD)      { src = wo; off = i - 3 * DD; }
    else if (i < 4 * DD + DF) { src = w1; off = i - 4 * DD; }
    else                      { src = w2; off = i - 4 * DD - DF; }
    float4 v = *reinterpret_cast<const float4*>(src + off);
    ushortx4 o = { f2b(v.x), f2b(v.y), f2b(v.z), f2b(v.w) };
    *reinterpret_cast<ushortx4*>(out + i) = o;
  }
}

// concat per-layer qkv biases -> bqkv_all[L][3072]
__global__ __launch_bounds__(256) void k_bcat(const float* __restrict__ bq,
    const float* __restrict__ bk, const float* __restrict__ bv,
    float* __restrict__ out)
{
  int i = blockIdx.x * 256 + threadIdx.x;
  int l = i / 3072, j = i - l * 3072;
  float v = (j < D_) ? bq[l * D_ + j] : (j < 2 * D_) ? bk[l * D_ + j - D_]
                                                     : bv[l * D_ + j - 2 * D_];
  out[i] = v;
}

// ---------------------------------------------------------------------------
// bf16 MFMA GEMM: C[M,N] = A[M,K] @ Wt[N,K]^T + bias
// ---------------------------------------------------------------------------
template<int RELU, int OUTBF16>
__global__ __launch_bounds__(256) void k_gemm_bf16(
    const unsigned short* __restrict__ A, const unsigned short* __restrict__ Wt,
    const float* __restrict__ bias, void* __restrict__ C,
    int M, int N, int K, int ldc)
{
  __shared__ unsigned short As[128][32];
  __shared__ unsigned short Bs[128][32];
  int t = threadIdx.x;
  int lane = t & 63;
  int wid = t >> 6;
  int bm = blockIdx.y * 128;
  int bn = blockIdx.x * 128;
  int wr = wid >> 1, wc = wid & 1;

  const unsigned short* Ag = A + (size_t)(bm + wid * 32 + (lane >> 2)) * K + (lane & 3) * 8;
  const unsigned short* Bg = Wt + (size_t)(bn + wid * 32 + (lane >> 2)) * K + (lane & 3) * 8;

  f32x4 acc[4][4] = {};
  int fr = lane & 15;
  int kc = lane >> 4;

  for (int kt = 0; kt < K; kt += 32) {
#pragma unroll
    for (int j = 0; j < 2; ++j) {
      gload16(Ag + (size_t)j * 16 * K + kt, &As[wid * 32 + j * 16][0]);
      gload16(Bg + (size_t)j * 16 * K + kt, &Bs[wid * 32 + j * 16][0]);
    }
    __syncthreads();
    bf16x8 af[4], bfv[4];
#pragma unroll
    for (int m = 0; m < 4; ++m)
      af[m] = *reinterpret_cast<const bf16x8*>(&As[wr * 64 + m * 16 + fr][kc * 8]);
#pragma unroll
    for (int n = 0; n < 4; ++n)
      bfv[n] = *reinterpret_cast<const bf16x8*>(&Bs[wc * 64 + n * 16 + fr][kc * 8]);
#pragma unroll
    for (int m = 0; m < 4; ++m)
#pragma unroll
      for (int n = 0; n < 4; ++n)
        acc[m][n] = __builtin_amdgcn_mfma_f32_16x16x32_bf16(af[m], bfv[n], acc[m][n], 0, 0, 0);
    __syncthreads();
  }

  int fq = lane >> 4;
#pragma unroll
  for (int n = 0; n < 4; ++n) {
    int col = bn + wc * 64 + n * 16 + fr;
    float bv = bias[col];
#pragma unroll
    for (int m = 0; m < 4; ++m) {
      int row = bm + wr * 64 + m * 16 + fq * 4;
#pragma unroll
      for (int j = 0; j < 4; ++j) {
        float v = acc[m][n][j] + bv;
        if (RELU) v = fmaxf(v, 0.f);
        if (OUTBF16)
          ((unsigned short*)C)[(size_t)(row + j) * ldc + col] = f2b(v);
        else
          ((float*)C)[(size_t)(row + j) * ldc + col] = v;
      }
    }
  }
}

// ---------------------------------------------------------------------------
// MFMA sparse attention: one wave per (b, head).
// QK^T (MFMA) -> scores in LDS (f32) -> per-lane top-5 + exp (split-bf16 P)
// -> PV (MFMA, P_hi + P_lo for ~fp32-P accuracy) -> O scaled by 1/denom.
// ---------------------------------------------------------------------------
__global__ __launch_bounds__(64) void k_attn(const unsigned short* __restrict__ qkv,
    const int* __restrict__ mask, unsigned short* __restrict__ ao)
{
  __shared__ float sc[64][68];
  __shared__ unsigned short ph[64][68];
  __shared__ unsigned short plo[64][68];
  __shared__ unsigned short vT[64][68];
  __shared__ float dnm[64];

  int blk = blockIdx.x;
  int b = blk >> 4, hh = blk & 15;
  int l = threadIdx.x;
  int cl = l & 15, kg = l >> 4;
  const unsigned short* base = qkv + (size_t)(b * S_) * 3072 + hh * 64;

  // --- V transposed into LDS: lane l = d index, iterate key rows
  {
    const unsigned short* vp = base + 2048 + l;
#pragma unroll 4
    for (int k = 0; k < S_; ++k)
      vT[l][k] = vp[(size_t)k * 3072];
#pragma unroll
    for (int k = S_; k < 64; ++k) vT[l][k] = 0;
  }

  // --- Q, K fragments (rows >= 52 zero-padded)
  bf16x8 qa[4][2], kb[4][2];
#pragma unroll
  for (int mi = 0; mi < 4; ++mi) {
    int row = mi * 16 + cl;
    bool ok = (row < S_);
    const unsigned short* qp = base + (size_t)row * 3072 + kg * 8;
#pragma unroll
    for (int ks = 0; ks < 2; ++ks) {
      bf16x8 z = {};
      qa[mi][ks] = ok ? *reinterpret_cast<const bf16x8*>(qp + ks * 32) : z;
      kb[mi][ks] = ok ? *reinterpret_cast<const bf16x8*>(qp + 1024 + ks * 32) : z;
    }
  }

  // --- QK^T
  f32x4 acc[4][4] = {};
#pragma unroll
  for (int ks = 0; ks < 2; ++ks)
#pragma unroll
    for (int mi = 0; mi < 4; ++mi)
#pragma unroll
      for (int ci = 0; ci < 4; ++ci)
        acc[mi][ci] = __builtin_amdgcn_mfma_f32_16x16x32_bf16(qa[mi][ks], kb[ci][ks], acc[mi][ci], 0, 0, 0);

  // --- scale + mask -> LDS scores (f32)
  int vld[4];
#pragma unroll
  for (int ci = 0; ci < 4; ++ci) {
    int col = ci * 16 + cl;
    vld[ci] = (col < S_) ? mask[b * S_ + col] : 0;
  }
#pragma unroll
  for (int mi = 0; mi < 4; ++mi)
#pragma unroll
    for (int ci = 0; ci < 4; ++ci)
#pragma unroll
      for (int j = 0; j < 4; ++j)
        sc[mi * 16 + kg * 4 + j][ci * 16 + cl] = vld[ci] ? acc[mi][ci][j] * SCALE_ : -1e9f;

  __syncthreads();

  // --- per-row top-5 threshold + exp; write split-bf16 P, store 1/denom
  if (l < S_) {
    float v0 = -3e38f, v1 = -3e38f, v2 = -3e38f, v3 = -3e38f, v4 = -3e38f;
    const float4* rp = reinterpret_cast<const float4*>(&sc[l][0]);
#pragma unroll
    for (int c4 = 0; c4 < 13; ++c4) {
      float4 x = rp[c4];
      float xs[4] = { x.x, x.y, x.z, x.w };
#pragma unroll
      for (int u = 0; u < 4; ++u) {
        float xv = xs[u];
        if      (xv > v0) { v4 = v3; v3 = v2; v2 = v1; v1 = v0; v0 = xv; }
        else if (xv > v1) { v4 = v3; v3 = v2; v2 = v1; v1 = xv; }
        else if (xv > v2) { v4 = v3; v3 = v2; v2 = xv; }
        else if (xv > v3) { v4 = v3; v3 = xv; }
        else if (xv > v4) { v4 = xv; }
      }
    }
    float thr = v4;
    float m = fmaxf(v0, 0.f);
    float denom = 0.f;
    for (int c = 0; c < S_; ++c) {
      float xv = sc[l][c];
      float sp = (xv >= thr) ? xv : 0.f;
      float e = __expf(sp - m);
      denom += e;
      unsigned short hi = f2b(e);
      ph[l][c] = hi;
      plo[l][c] = f2b(e - b2f(hi));
    }
#pragma unroll
    for (int c = S_; c < 64; ++c) { ph[l][c] = 0; plo[l][c] = 0; }
    dnm[l] = 1.f / denom;
  }
  __syncthreads();

  // --- PV with split P: O = (P_hi + P_lo) @ V
  f32x4 o[4][4] = {};
#pragma unroll
  for (int ks = 0; ks < 2; ++ks) {
    bf16x8 vf[4];
#pragma unroll
    for (int di = 0; di < 4; ++di)
      vf[di] = *reinterpret_cast<const bf16x8*>(&vT[di * 16 + cl][ks * 32 + kg * 8]);
#pragma unroll
    for (int mi = 0; mi < 4; ++mi) {
      bf16x8 ahi = *reinterpret_cast<const bf16x8*>(&ph[mi * 16 + cl][ks * 32 + kg * 8]);
      bf16x8 alo = *reinterpret_cast<const bf16x8*>(&plo[mi * 16 + cl][ks * 32 + kg * 8]);
#pragma unroll
      for (int di = 0; di < 4; ++di) {
        o[mi][di] = __builtin_amdgcn_mfma_f32_16x16x32_bf16(ahi, vf[di], o[mi][di], 0, 0, 0);
        o[mi][di] = __builtin_amdgcn_mfma_f32_16x16x32_bf16(alo, vf[di], o[mi][di], 0, 0, 0);
      }
    }
  }

  // --- epilogue: scale by 1/denom, write bf16 O
#pragma unroll
  for (int mi = 0; mi < 4; ++mi) {
    int row = mi * 16 + kg * 4;
    if (row < S_) {
#pragma unroll
      for (int j = 0; j < 4; ++j) {
        int r = row + j;
        float inv = dnm[r];
        unsigned short* aop = ao + (size_t)(b * S_ + r) * D_ + hh * DK_;
#pragma unroll
        for (int di = 0; di < 4; ++di)
          aop[di * 16 + cl] = f2b(o[mi][di][j] * inv);
      }
    }
  }
}

// ---------------------------------------------------------------------------
// h = LayerNorm(h + r); writes fp32 h and bf16 hb
// ---------------------------------------------------------------------------
__global__ __launch_bounds__(256) void k_add_ln(float* __restrict__ h,
    const float* __restrict__ r, const float* __restrict__ g,
    const float* __restrict__ bb, unsigned short* __restrict__ hb)
{
  int row = blockIdx.x;
  size_t base = (size_t)row * D_;
  int t = threadIdx.x;
  float xs[4];
  float s1 = 0.f, s2 = 0.f;
#pragma unroll
  for (int i = 0; i < 4; ++i) {
    int d = t + i * 256;
    float xv = h[base + d] + r[base + d];
    xs[i] = xv;
    s1 += xv;
    s2 += xv * xv;
  }
#pragma unroll
  for (int off = 32; off; off >>= 1) {
    s1 += __shfl_down(s1, off);
    s2 += __shfl_down(s2, off);
  }
  __shared__ float red[8];
  int lane = t & 63, wid = t >> 6;
  if (lane == 0) { red[wid] = s1; red[4 + wid] = s2; }
  __syncthreads();
  if (t == 0) {
    red[0] = red[0] + red[1] + red[2] + red[3];
    red[4] = red[4] + red[5] + red[6] + red[7];
  }
  __syncthreads();
  float mean = red[0] / (float)D_;
  float var  = red[4] / (float)D_ - mean * mean;
  float inv  = rsqrtf(var + EPS_);
#pragma unroll
  for (int i = 0; i < 4; ++i) {
    int d = t + i * 256;
    float v = (xs[i] - mean) * inv * g[d] + bb[d];
    h[base + d] = v;
    hb[base + d] = f2b(v);
  }
}

// ---------------------------------------------------------------------------
__global__ __launch_bounds__(256) void k_final(const float* __restrict__ h,
    const float* __restrict__ Wout, const float* __restrict__ bout,
    float* __restrict__ y)
{
  int b = blockIdx.x;
  const float* hr = h + (size_t)(b * S_ + (S_ - 1)) * D_;
  int t = threadIdx.x;
  float p0 = 0.f, p1 = 0.f, p2 = 0.f;
  for (int d = t; d < D_; d += 256) {
    float xv = hr[d];
    p0 += xv * Wout[d];
    p1 += xv * Wout[D_ + d];
    p2 += xv * Wout[2 * D_ + d];
  }
#pragma unroll
  for (int off = 32; off; off >>= 1) {
    p0 += __shfl_down(p0, off);
    p1 += __shfl_down(p1, off);
    p2 += __shfl_down(p2, off);
  }
  __shared__ float red[12];
  int lane = t & 63, wid = t >> 6;
  if (lane == 0) { red[wid] = p0; red[4 + wid] = p1; red[8 + wid] = p2; }
  __syncthreads();
  if (t == 0) {
    y[b * 3 + 0] = red[0] + red[1] + red[2]  + red[3]  + bout[0];
    y[b * 3 + 1] = red[4] + red[5] + red[6]  + red[7]  + bout[1];
    y[b * 3 + 2] = red[8] + red[9] + red[10] + red[11] + bout[2];
  }
}

// ---------------------------------------------------------------------------
extern "C" void kernel_launch(void* const* d_in, const int* in_sizes, int n_in,
                              void* d_out, int out_size, void* d_ws, size_t ws_size,
                              hipStream_t stream)
{
  const int*   x    = (const int*)d_in[0];
  const float* aemb = (const float*)d_in[1];
  const float* sept = (const float*)d_in[2];
  const float* bng  = (const float*)d_in[3];
  const float* bnb  = (const float*)d_in[4];
  const float* Wq = (const float*)d_in[5];  const float* bq = (const float*)d_in[6];
  const float* Wk = (const float*)d_in[7];  const float* bk = (const float*)d_in[8];
  const float* Wv = (const float*)d_in[9];  const float* bv = (const float*)d_in[10];
  const float* Wo = (const float*)d_in[11]; const float* bo = (const float*)d_in[12];
  const float* W1 = (const float*)d_in[13]; const float* b1 = (const float*)d_in[14];
  const float* W2 = (const float*)d_in[15]; const float* b2 = (const float*)d_in[16];
  const float* ln1g = (const float*)d_in[17]; const float* ln1b = (const float*)d_in[18];
  const float* ln2g = (const float*)d_in[19]; const float* ln2b = (const float*)d_in[20];
  const float* Wout = (const float*)d_in[21]; const float* bout = (const float*)d_in[22];
  float* out = (float*)d_out;

  float* ws = (float*)d_ws;
  const size_t TD = (size_t)T_ * D_;
  const size_t DD = (size_t)D_ * D_;
  const size_t DF = (size_t)DFF_ * D_;
  float* h   = ws;                                                  // TD f32
  float* tmp = ws + TD;                                             // TD f32
  unsigned short* hb   = (unsigned short*)(ws + 2 * TD);            // TD bf16
  unsigned short* qkvb = (unsigned short*)(ws + 2 * TD + TD / 2);   // 3TD bf16
  unsigned short* aob  = (unsigned short*)(ws + 4 * TD);            // TD bf16
  unsigned short* ffb  = (unsigned short*)(ws + 4 * TD + TD / 2);   // 4TD bf16
  unsigned short* wbuf = (unsigned short*)(ws + 6 * TD + TD / 2);   // (4DD+2DF) bf16
  float* bqkv = ws + 6 * TD + TD / 2 + (4 * DD + 2 * DF) / 2;       // L*3072 f32
  float* stats = bqkv + L_ * 3072;
  float* part  = stats + 2 * S_;
  int*   mask  = (int*)(part + 2 * S_ * B_);

  k_embed<<<T_, 256, 0, stream>>>(x, aemb, sept, h, part, mask);
  k_bn_reduce<<<S_, 128, 0, stream>>>(part, stats);
  k_bn_apply<<<T_, 256, 0, stream>>>(h, stats, bng, bnb, hb);
  k_bcat<<<(L_ * 3072) / 256, 256, 0, stream>>>(bq, bk, bv, bqkv);

  for (int l = 0; l < L_; ++l) {
    k_wconv<<<3072, 256, 0, stream>>>(Wq + l * DD, Wk + l * DD, Wv + l * DD,
                                      Wo + l * DD, W1 + l * DF, W2 + l * DF, wbuf);
    k_gemm_bf16<0, 1><<<dim3(24, 52), 256, 0, stream>>>(hb, wbuf, bqkv + l * 3072,
        qkvb, T_, 3072, D_, 3072);
    k_attn<<<B_ * H_, 64, 0, stream>>>(qkvb, mask, aob);
    k_gemm_bf16<0, 0><<<dim3(8, 52), 256, 0, stream>>>(aob, wbuf + 3 * DD, bo + l * D_,
        tmp, T_, D_, D_, D_);
    k_add_ln<<<T_, 256, 0, stream>>>(h, tmp, ln1g + l * D_, ln1b + l * D_, hb);
    k_gemm_bf16<1, 1><<<dim3(32, 52), 256, 0, stream>>>(hb, wbuf + 4 * DD, b1 + l * DFF_,
        ffb, T_, DFF_, D_, DFF_);
    k_gemm_bf16<0, 0><<<dim3(8, 52), 256, 0, stream>>>(ffb, wbuf + 4 * DD + DF, b2 + l * D_,
        tmp, T_, D_, DFF_, D_);
    k_add_ln<<<T_, 256, 0, stream>>>(h, tmp, ln2g + l * D_, ln2b + l * D_, hb);
  }
  k_final<<<B_, 256, 0, stream>>>(h, Wout, bout, out);
}

// Round 4
// 2636.198 us; speedup vs baseline: 8.0419x; 1.1162x over previous
//
#include <hip/hip_runtime.h>
#include <cstddef>
#include <cstdint>

#define B_    128
#define S_    52
#define D_    1024
#define H_    16
#define L_    8
#define DFF_  4096
#define DK_   64
#define T_    (B_*S_)
#define EPS_  1e-5f
#define SCALE_ 0.125f

typedef unsigned short ushortx4 __attribute__((ext_vector_type(4)));
typedef short  bf16x8 __attribute__((ext_vector_type(8)));
typedef float  f32x4  __attribute__((ext_vector_type(4)));

__device__ __forceinline__ unsigned short f2b(float f) {
  unsigned int u = __builtin_bit_cast(unsigned int, f);
  u = u + 0x7fffu + ((u >> 16) & 1u);
  return (unsigned short)(u >> 16);
}
__device__ __forceinline__ float b2f(unsigned short b) {
  unsigned int u = ((unsigned int)b) << 16;
  return __builtin_bit_cast(float, u);
}
__device__ __forceinline__ void gload16(const void* g, void* l) {
  __builtin_amdgcn_global_load_lds((const __attribute__((address_space(1))) unsigned int*)g,
      (__attribute__((address_space(3))) unsigned int*)l, 16, 0, 0);
}

// ---------------------------------------------------------------------------
// Embedding + BN partial stats
// ---------------------------------------------------------------------------
__global__ __launch_bounds__(256) void k_embed(const int* __restrict__ x,
    const float* __restrict__ aemb, const float* __restrict__ sept,
    float* __restrict__ h, float* __restrict__ part, int* __restrict__ mask)
{
  int row = blockIdx.x;
  int b = row / S_;
  int s = row - b * S_;
  const int* xr = x + (size_t)row * 3;
  int x0 = xr[0], x1 = xr[1], x2 = xr[2];
  bool issep = (x0 == 100) && (x1 == 0) && (x2 == 2);
  bool ispad = (x0 == 100) && (x1 == 0) && (x2 == 0);
  int t = threadIdx.x;
  if (t == 0) mask[row] = ispad ? 0 : 1;
  const float* src = issep ? sept : (aemb + (size_t)x2 * D_);
  size_t base = (size_t)row * D_;
  float s1 = 0.f, s2 = 0.f;
#pragma unroll
  for (int i = 0; i < 4; ++i) {
    int d = t + i * 256;
    float v = src[d];
    h[base + d] = v;
    s1 += v;
    s2 += v * v;
  }
#pragma unroll
  for (int off = 32; off; off >>= 1) {
    s1 += __shfl_down(s1, off);
    s2 += __shfl_down(s2, off);
  }
  __shared__ float red[8];
  int lane = t & 63, wid = t >> 6;
  if (lane == 0) { red[wid] = s1; red[4 + wid] = s2; }
  __syncthreads();
  if (t == 0) {
    part[(size_t)s * B_ + b]        = red[0] + red[1] + red[2] + red[3];
    part[(size_t)(S_ + s) * B_ + b] = red[4] + red[5] + red[6] + red[7];
  }
}

__global__ __launch_bounds__(128) void k_bn_reduce(const float* __restrict__ part,
                                                   float* __restrict__ stats)
{
  int s = blockIdx.x;
  int t = threadIdx.x;
  float s1 = part[(size_t)s * B_ + t];
  float s2 = part[(size_t)(S_ + s) * B_ + t];
#pragma unroll
  for (int off = 32; off; off >>= 1) {
    s1 += __shfl_down(s1, off);
    s2 += __shfl_down(s2, off);
  }
  __shared__ float red[4];
  int lane = t & 63, wid = t >> 6;
  if (lane == 0) { red[wid] = s1; red[2 + wid] = s2; }
  __syncthreads();
  if (t == 0) {
    stats[s]      = red[0] + red[1];
    stats[S_ + s] = red[2] + red[3];
  }
}

// BN apply, writes fp32 h and bf16 hb
__global__ __launch_bounds__(256) void k_bn_apply(float* __restrict__ h,
    const float* __restrict__ stats, const float* __restrict__ g,
    const float* __restrict__ bb, unsigned short* __restrict__ hb)
{
  int row = blockIdx.x;
  int s = row % S_;
  const float cnt = (float)(B_ * D_);
  float mu  = stats[s] / cnt;
  float var = stats[S_ + s] / cnt - mu * mu;
  float sc  = rsqrtf(var + EPS_) * g[s];
  float off = bb[s] - mu * sc;
  size_t base = (size_t)row * D_;
  int t = threadIdx.x;
#pragma unroll
  for (int i = 0; i < 4; ++i) {
    int d = t + i * 256;
    float v = h[base + d] * sc + off;
    h[base + d] = v;
    hb[base + d] = f2b(v);
  }
}

// per-layer fused weight conversion: [q|k|v|o|w1|w2] -> wbuf
__global__ __launch_bounds__(256) void k_wconv(
    const float* __restrict__ wq, const float* __restrict__ wk,
    const float* __restrict__ wv, const float* __restrict__ wo,
    const float* __restrict__ w1, const float* __restrict__ w2,
    unsigned short* __restrict__ out)
{
  const size_t DD = (size_t)D_ * D_;
  const size_t DF = (size_t)DFF_ * D_;
  const size_t total = 4 * DD + 2 * DF;
  size_t stride = (size_t)gridDim.x * 256 * 4;
  for (size_t i = ((size_t)blockIdx.x * 256 + threadIdx.x) * 4; i < total; i += stride) {
    const float* src; size_t off;
    if      (i < DD)          { src = wq; off = i; }
    else if (i < 2 * DD)      { src = wk; off = i - DD; }
    else if (i < 3 * DD)      { src = wv; off = i - 2 * DD; }
    else if (i < 4 * DD)      { src = wo; off = i - 3 * DD; }
    else if (i < 4 * DD + DF) { src = w1; off = i - 4 * DD; }
    else                      { src = w2; off = i - 4 * DD - DF; }
    float4 v = *reinterpret_cast<const float4*>(src + off);
    ushortx4 o = { f2b(v.x), f2b(v.y), f2b(v.z), f2b(v.w) };
    *reinterpret_cast<ushortx4*>(out + i) = o;
  }
}

// concat per-layer qkv biases -> bqkv_all[L][3072]
__global__ __launch_bounds__(256) void k_bcat(const float* __restrict__ bq,
    const float* __restrict__ bk, const float* __restrict__ bv,
    float* __restrict__ out)
{
  int i = blockIdx.x * 256 + threadIdx.x;
  int l = i / 3072, j = i - l * 3072;
  float v = (j < D_) ? bq[l * D_ + j] : (j < 2 * D_) ? bk[l * D_ + j - D_]
                                                     : bv[l * D_ + j - 2 * D_];
  out[i] = v;
}

// ---------------------------------------------------------------------------
// Pipelined bf16 MFMA GEMM: C[M,N] = A[M,K] @ Wt[N,K]^T + bias
// 256x128 tile, BK=64, 8 waves (4Mx2N), 3 LDS buffers, depth-2 prefetch,
// counted vmcnt (never drain in steady state), raw s_barrier, T2 XOR swizzle
// (inverse-swizzled global source + swizzled ds_read), XCD block swizzle.
// Requires: M%256==0, N%128==0, K%64==0, grid%8==0.
// ---------------------------------------------------------------------------
template<int RELU, int OUTBF16>
__global__ __launch_bounds__(512) void k_gemm8(
    const unsigned short* __restrict__ A, const unsigned short* __restrict__ Wt,
    const float* __restrict__ bias, void* __restrict__ C,
    int Mtiles, int Ntiles, int K, int ldc)
{
  __shared__ unsigned short lds[3 * 24576];   // 3 x (A 256x64 + B 128x64) bf16 = 144 KB
  const int tid = threadIdx.x;
  const int w = tid >> 6, l = tid & 63;

  const int nwg = Mtiles * Ntiles;
  int id = blockIdx.x;
  int swz = (id & 7) * (nwg >> 3) + (id >> 3);      // bijective: nwg % 8 == 0
  int bym = swz % Mtiles, bxn = swz / Mtiles;       // consecutive swz share bxn (W-panel)
  const int bm = bym * 256, bn = bxn * 128;

  // --- staging addresses (lane-swizzled global source, linear LDS dest) ---
  const int srow = l >> 3;                                   // 0..7
  const unsigned inrow = ((l & 7) << 4) ^ ((l & 0x38) << 1); // (l%8)*16 ^ ((l/8)%8)*16
  const char* gA = (const char*)A + (size_t)(bm + w * 32 + srow) * ((size_t)K * 2) + inrow;
  const char* gB = (const char*)Wt + (size_t)(bn + w * 16 + srow) * ((size_t)K * 2) + inrow;
  const size_t rj = (size_t)8 * K * 2;                       // 8-row stride (bytes)
  const int ldsA0 = w * 2048;            // ushort units; + buf*24576 + j*512
  const int ldsB0 = 16384 + w * 1024;

#define STAGE8(tt, bb) do {                                   \
    size_t kb = (size_t)(tt) * 128;                           \
    unsigned short* la = lds + (bb) * 24576 + ldsA0;          \
    unsigned short* lb = lds + (bb) * 24576 + ldsB0;          \
    gload16(gA + kb,          la);                            \
    gload16(gA + kb + rj,     la + 512);                      \
    gload16(gA + kb + 2 * rj, la + 1024);                     \
    gload16(gA + kb + 3 * rj, la + 1536);                     \
    gload16(gB + kb,          lb);                            \
    gload16(gB + kb + rj,     lb + 512);                      \
  } while (0)

  // --- fragment read addresses (byte offsets within buffer, XOR-swizzled) ---
  const int fr = l & 15, kg = l >> 4;
  const int wr = w >> 1, wcn = w & 1;
  const unsigned sw = (fr & 7) << 4;
  const unsigned colk0 = ((unsigned)(kg * 16)) ^ sw;
  const unsigned colk1 = ((unsigned)(64 + kg * 16)) ^ sw;
  const unsigned aRow0 = (unsigned)(wr * 64 + fr) * 128;          // + m*2048
  const unsigned bRow0 = 32768u + (unsigned)(wcn * 64 + fr) * 128; // + n*2048

  f32x4 acc[4][4] = {};
  const int NT = K >> 6;

  // prologue: stage K-tiles 0,1 ; wait tile 0 landed (6 newest outstanding)
  STAGE8(0, 0);
  STAGE8(1, 1);
  asm volatile("s_waitcnt vmcnt(6)" ::: "memory");
  __builtin_amdgcn_sched_barrier(0);
  __builtin_amdgcn_s_barrier();
  __builtin_amdgcn_sched_barrier(0);

  int cur = 0;
  for (int t = 0; t < NT; ++t) {
    if (t + 2 < NT) {
      int sb = cur + 2; if (sb >= 3) sb -= 3;
      STAGE8(t + 2, sb);
    }
    const char* bp = (const char*)(lds + cur * 24576);
    bf16x8 bfr[4][2];
#pragma unroll
    for (int n = 0; n < 4; ++n) {
      bfr[n][0] = *(const bf16x8*)(bp + bRow0 + n * 2048 + colk0);
      bfr[n][1] = *(const bf16x8*)(bp + bRow0 + n * 2048 + colk1);
    }
#pragma unroll
    for (int m = 0; m < 4; ++m) {
      bf16x8 a0 = *(const bf16x8*)(bp + aRow0 + m * 2048 + colk0);
      bf16x8 a1 = *(const bf16x8*)(bp + aRow0 + m * 2048 + colk1);
#pragma unroll
      for (int n = 0; n < 4; ++n) {
        acc[m][n] = __builtin_amdgcn_mfma_f32_16x16x32_bf16(a0, bfr[n][0], acc[m][n], 0, 0, 0);
        acc[m][n] = __builtin_amdgcn_mfma_f32_16x16x32_bf16(a1, bfr[n][1], acc[m][n], 0, 0, 0);
      }
    }
    if (t + 1 < NT) {
      if (t + 2 < NT) { asm volatile("s_waitcnt vmcnt(6)" ::: "memory"); }
      else            { asm volatile("s_waitcnt vmcnt(0)" ::: "memory"); }
      __builtin_amdgcn_sched_barrier(0);
      __builtin_amdgcn_s_barrier();
      __builtin_amdgcn_sched_barrier(0);
    }
    cur = (cur == 2) ? 0 : cur + 1;
  }
#undef STAGE8

  // --- epilogue ---
#pragma unroll
  for (int n = 0; n < 4; ++n) {
    int col = bn + wcn * 64 + n * 16 + fr;
    float bv = bias[col];
#pragma unroll
    for (int m = 0; m < 4; ++m) {
      int row0 = bm + wr * 64 + m * 16 + kg * 4;
#pragma unroll
      for (int j = 0; j < 4; ++j) {
        float v = acc[m][n][j] + bv;
        if (RELU) v = fmaxf(v, 0.f);
        if (OUTBF16)
          ((unsigned short*)C)[(size_t)(row0 + j) * ldc + col] = f2b(v);
        else
          ((float*)C)[(size_t)(row0 + j) * ldc + col] = v;
      }
    }
  }
}

// ---------------------------------------------------------------------------
// MFMA sparse attention: one wave per (b, head).
// ---------------------------------------------------------------------------
__global__ __launch_bounds__(64) void k_attn(const unsigned short* __restrict__ qkv,
    const int* __restrict__ mask, unsigned short* __restrict__ ao)
{
  __shared__ float sc[64][68];
  __shared__ unsigned short ph[64][68];
  __shared__ unsigned short plo[64][68];
  __shared__ unsigned short vT[64][68];
  __shared__ float dnm[64];

  int blk = blockIdx.x;
  int b = blk >> 4, hh = blk & 15;
  int l = threadIdx.x;
  int cl = l & 15, kg = l >> 4;
  const unsigned short* base = qkv + (size_t)(b * S_) * 3072 + hh * 64;

  {
    const unsigned short* vp = base + 2048 + l;
#pragma unroll 4
    for (int k = 0; k < S_; ++k)
      vT[l][k] = vp[(size_t)k * 3072];
#pragma unroll
    for (int k = S_; k < 64; ++k) vT[l][k] = 0;
  }

  bf16x8 qa[4][2], kb[4][2];
#pragma unroll
  for (int mi = 0; mi < 4; ++mi) {
    int row = mi * 16 + cl;
    bool ok = (row < S_);
    const unsigned short* qp = base + (size_t)row * 3072 + kg * 8;
#pragma unroll
    for (int ks = 0; ks < 2; ++ks) {
      bf16x8 z = {};
      qa[mi][ks] = ok ? *reinterpret_cast<const bf16x8*>(qp + ks * 32) : z;
      kb[mi][ks] = ok ? *reinterpret_cast<const bf16x8*>(qp + 1024 + ks * 32) : z;
    }
  }

  f32x4 acc[4][4] = {};
#pragma unroll
  for (int ks = 0; ks < 2; ++ks)
#pragma unroll
    for (int mi = 0; mi < 4; ++mi)
#pragma unroll
      for (int ci = 0; ci < 4; ++ci)
        acc[mi][ci] = __builtin_amdgcn_mfma_f32_16x16x32_bf16(qa[mi][ks], kb[ci][ks], acc[mi][ci], 0, 0, 0);

  int vld[4];
#pragma unroll
  for (int ci = 0; ci < 4; ++ci) {
    int col = ci * 16 + cl;
    vld[ci] = (col < S_) ? mask[b * S_ + col] : 0;
  }
#pragma unroll
  for (int mi = 0; mi < 4; ++mi)
#pragma unroll
    for (int ci = 0; ci < 4; ++ci)
#pragma unroll
      for (int j = 0; j < 4; ++j)
        sc[mi * 16 + kg * 4 + j][ci * 16 + cl] = vld[ci] ? acc[mi][ci][j] * SCALE_ : -1e9f;

  __syncthreads();

  if (l < S_) {
    float v0 = -3e38f, v1 = -3e38f, v2 = -3e38f, v3 = -3e38f, v4 = -3e38f;
    const float4* rp = reinterpret_cast<const float4*>(&sc[l][0]);
#pragma unroll
    for (int c4 = 0; c4 < 13; ++c4) {
      float4 x = rp[c4];
      float xs[4] = { x.x, x.y, x.z, x.w };
#pragma unroll
      for (int u = 0; u < 4; ++u) {
        float xv = xs[u];
        if      (xv > v0) { v4 = v3; v3 = v2; v2 = v1; v1 = v0; v0 = xv; }
        else if (xv > v1) { v4 = v3; v3 = v2; v2 = v1; v1 = xv; }
        else if (xv > v2) { v4 = v3; v3 = v2; v2 = xv; }
        else if (xv > v3) { v4 = v3; v3 = xv; }
        else if (xv > v4) { v4 = xv; }
      }
    }
    float thr = v4;
    float m = fmaxf(v0, 0.f);
    float denom = 0.f;
    for (int c = 0; c < S_; ++c) {
      float xv = sc[l][c];
      float sp = (xv >= thr) ? xv : 0.f;
      float e = __expf(sp - m);
      denom += e;
      unsigned short hi = f2b(e);
      ph[l][c] = hi;
      plo[l][c] = f2b(e - b2f(hi));
    }
#pragma unroll
    for (int c = S_; c < 64; ++c) { ph[l][c] = 0; plo[l][c] = 0; }
    dnm[l] = 1.f / denom;
  }
  __syncthreads();

  f32x4 o[4][4] = {};
#pragma unroll
  for (int ks = 0; ks < 2; ++ks) {
    bf16x8 vf[4];
#pragma unroll
    for (int di = 0; di < 4; ++di)
      vf[di] = *reinterpret_cast<const bf16x8*>(&vT[di * 16 + cl][ks * 32 + kg * 8]);
#pragma unroll
    for (int mi = 0; mi < 4; ++mi) {
      bf16x8 ahi = *reinterpret_cast<const bf16x8*>(&ph[mi * 16 + cl][ks * 32 + kg * 8]);
      bf16x8 alo = *reinterpret_cast<const bf16x8*>(&plo[mi * 16 + cl][ks * 32 + kg * 8]);
#pragma unroll
      for (int di = 0; di < 4; ++di) {
        o[mi][di] = __builtin_amdgcn_mfma_f32_16x16x32_bf16(ahi, vf[di], o[mi][di], 0, 0, 0);
        o[mi][di] = __builtin_amdgcn_mfma_f32_16x16x32_bf16(alo, vf[di], o[mi][di], 0, 0, 0);
      }
    }
  }

#pragma unroll
  for (int mi = 0; mi < 4; ++mi) {
    int row = mi * 16 + kg * 4;
    if (row < S_) {
#pragma unroll
      for (int j = 0; j < 4; ++j) {
        int r = row + j;
        float inv = dnm[r];
        unsigned short* aop = ao + (size_t)(b * S_ + r) * D_ + hh * DK_;
#pragma unroll
        for (int di = 0; di < 4; ++di)
          aop[di * 16 + cl] = f2b(o[mi][di][j] * inv);
      }
    }
  }
}

// ---------------------------------------------------------------------------
// h = LayerNorm(h + r); writes fp32 h and bf16 hb
// ---------------------------------------------------------------------------
__global__ __launch_bounds__(256) void k_add_ln(float* __restrict__ h,
    const float* __restrict__ r, const float* __restrict__ g,
    const float* __restrict__ bb, unsigned short* __restrict__ hb)
{
  int row = blockIdx.x;
  size_t base = (size_t)row * D_;
  int t = threadIdx.x;
  float xs[4];
  float s1 = 0.f, s2 = 0.f;
#pragma unroll
  for (int i = 0; i < 4; ++i) {
    int d = t + i * 256;
    float xv = h[base + d] + r[base + d];
    xs[i] = xv;
    s1 += xv;
    s2 += xv * xv;
  }
#pragma unroll
  for (int off = 32; off; off >>= 1) {
    s1 += __shfl_down(s1, off);
    s2 += __shfl_down(s2, off);
  }
  __shared__ float red[8];
  int lane = t & 63, wid = t >> 6;
  if (lane == 0) { red[wid] = s1; red[4 + wid] = s2; }
  __syncthreads();
  if (t == 0) {
    red[0] = red[0] + red[1] + red[2] + red[3];
    red[4] = red[4] + red[5] + red[6] + red[7];
  }
  __syncthreads();
  float mean = red[0] / (float)D_;
  float var  = red[4] / (float)D_ - mean * mean;
  float inv  = rsqrtf(var + EPS_);
#pragma unroll
  for (int i = 0; i < 4; ++i) {
    int d = t + i * 256;
    float v = (xs[i] - mean) * inv * g[d] + bb[d];
    h[base + d] = v;
    hb[base + d] = f2b(v);
  }
}

// ---------------------------------------------------------------------------
__global__ __launch_bounds__(256) void k_final(const float* __restrict__ h,
    const float* __restrict__ Wout, const float* __restrict__ bout,
    float* __restrict__ y)
{
  int b = blockIdx.x;
  const float* hr = h + (size_t)(b * S_ + (S_ - 1)) * D_;
  int t = threadIdx.x;
  float p0 = 0.f, p1 = 0.f, p2 = 0.f;
  for (int d = t; d < D_; d += 256) {
    float xv = hr[d];
    p0 += xv * Wout[d];
    p1 += xv * Wout[D_ + d];
    p2 += xv * Wout[2 * D_ + d];
  }
#pragma unroll
  for (int off = 32; off; off >>= 1) {
    p0 += __shfl_down(p0, off);
    p1 += __shfl_down(p1, off);
    p2 += __shfl_down(p2, off);
  }
  __shared__ float red[12];
  int lane = t & 63, wid = t >> 6;
  if (lane == 0) { red[wid] = p0; red[4 + wid] = p1; red[8 + wid] = p2; }
  __syncthreads();
  if (t == 0) {
    y[b * 3 + 0] = red[0] + red[1] + red[2]  + red[3]  + bout[0];
    y[b * 3 + 1] = red[4] + red[5] + red[6]  + red[7]  + bout[1];
    y[b * 3 + 2] = red[8] + red[9] + red[10] + red[11] + bout[2];
  }
}

// ---------------------------------------------------------------------------
extern "C" void kernel_launch(void* const* d_in, const int* in_sizes, int n_in,
                              void* d_out, int out_size, void* d_ws, size_t ws_size,
                              hipStream_t stream)
{
  const int*   x    = (const int*)d_in[0];
  const float* aemb = (const float*)d_in[1];
  const float* sept = (const float*)d_in[2];
  const float* bng  = (const float*)d_in[3];
  const float* bnb  = (const float*)d_in[4];
  const float* Wq = (const float*)d_in[5];  const float* bq = (const float*)d_in[6];
  const float* Wk = (const float*)d_in[7];  const float* bk = (const float*)d_in[8];
  const float* Wv = (const float*)d_in[9];  const float* bv = (const float*)d_in[10];
  const float* Wo = (const float*)d_in[11]; const float* bo = (const float*)d_in[12];
  const float* W1 = (const float*)d_in[13]; const float* b1 = (const float*)d_in[14];
  const float* W2 = (const float*)d_in[15]; const float* b2 = (const float*)d_in[16];
  const float* ln1g = (const float*)d_in[17]; const float* ln1b = (const float*)d_in[18];
  const float* ln2g = (const float*)d_in[19]; const float* ln2b = (const float*)d_in[20];
  const float* Wout = (const float*)d_in[21]; const float* bout = (const float*)d_in[22];
  float* out = (float*)d_out;

  float* ws = (float*)d_ws;
  const size_t TD = (size_t)T_ * D_;
  const size_t DD = (size_t)D_ * D_;
  const size_t DF = (size_t)DFF_ * D_;
  float* h   = ws;                                                  // TD f32
  float* tmp = ws + TD;                                             // TD f32
  unsigned short* hb   = (unsigned short*)(ws + 2 * TD);            // TD bf16
  unsigned short* qkvb = (unsigned short*)(ws + 2 * TD + TD / 2);   // 3TD bf16
  unsigned short* aob  = (unsigned short*)(ws + 4 * TD);            // TD bf16
  unsigned short* ffb  = (unsigned short*)(ws + 4 * TD + TD / 2);   // 4TD bf16
  unsigned short* wbuf = (unsigned short*)(ws + 6 * TD + TD / 2);   // (4DD+2DF) bf16
  float* bqkv = ws + 6 * TD + TD / 2 + (4 * DD + 2 * DF) / 2;       // L*3072 f32
  float* stats = bqkv + L_ * 3072;
  float* part  = stats + 2 * S_;
  int*   mask  = (int*)(part + 2 * S_ * B_);

  k_embed<<<T_, 256, 0, stream>>>(x, aemb, sept, h, part, mask);
  k_bn_reduce<<<S_, 128, 0, stream>>>(part, stats);
  k_bn_apply<<<T_, 256, 0, stream>>>(h, stats, bng, bnb, hb);
  k_bcat<<<(L_ * 3072) / 256, 256, 0, stream>>>(bq, bk, bv, bqkv);

  for (int l = 0; l < L_; ++l) {
    k_wconv<<<3072, 256, 0, stream>>>(Wq + l * DD, Wk + l * DD, Wv + l * DD,
                                      Wo + l * DD, W1 + l * DF, W2 + l * DF, wbuf);
    // QKV: M=6656 (26 Mtiles), N=3072 (24 Ntiles), K=1024
    k_gemm8<0, 1><<<26 * 24, 512, 0, stream>>>(hb, wbuf, bqkv + l * 3072,
        qkvb, 26, 24, 1024, 3072);
    k_attn<<<B_ * H_, 64, 0, stream>>>(qkvb, mask, aob);
    // O-proj: N=1024 (8 Ntiles), K=1024
    k_gemm8<0, 0><<<26 * 8, 512, 0, stream>>>(aob, wbuf + 3 * DD, bo + l * D_,
        tmp, 26, 8, 1024, 1024);
    k_add_ln<<<T_, 256, 0, stream>>>(h, tmp, ln1g + l * D_, ln1b + l * D_, hb);
    // FFN1: N=4096 (32 Ntiles), K=1024, relu
    k_gemm8<1, 1><<<26 * 32, 512, 0, stream>>>(hb, wbuf + 4 * DD, b1 + l * DFF_,
        ffb, 26, 32, 1024, 4096);
    // FFN2: N=1024 (8 Ntiles), K=4096
    k_gemm8<0, 0><<<26 * 8, 512, 0, stream>>>(ffb, wbuf + 4 * DD + DF, b2 + l * D_,
        tmp, 26, 8, 4096, 1024);
    k_add_ln<<<T_, 256, 0, stream>>>(h, tmp, ln2g + l * D_, ln2b + l * D_, hb);
  }
  k_final<<<B_, 256, 0, stream>>>(h, Wout, bout, out);
}